// Round 5
// baseline (19.895 us; speedup 1.0000x reference)
//
#include <hip/hip_runtime.h>

// Paste2dMulti: N=64, M=8, C=3, H=W=64, canvas l=256.
// Gather form. Thread = one output column x 8-row vertical strip.
// 2048 blocks x 256 thr = 8192 waves = 32 waves/CU: exactly one
// full-occupancy pass. Row logic is block-uniform -> scalar branches.
// Per surviving m, a lane issues up to 24 independent coalesced dword
// loads in one burst (good MLP); invalid columns skip via one divergent
// branch around the whole body (R3 style - fastest so far).

__device__ __forceinline__ float clamp01(float v) {
    return fminf(fmaxf(v, 0.0f), 1.0f);   // -> v_med3_f32
}

__global__ __launch_bounds__(256) void Paste2dMulti_kernel(
    const float* __restrict__ coords,   // [64][8][4]
    const float* __restrict__ images,   // [64][8][3][64][64]
    float* __restrict__ out)            // [64][1][256][256]
{
    const int bid  = blockIdx.x;       // 64 n * 32 bands
    const int n    = bid >> 5;         // block-uniform
    const int band = bid & 31;
    const int col  = threadIdx.x;      // 0..255
    const int r0   = band * 8;         // rows r0 .. r0+7 (block-uniform)

    const float fc = (float)col;
    const float* cb = coords + n * 32;
    const float* ib = images + (size_t)n * (8 * 3 * 4096);

    float acc[8] = {0.f, 0.f, 0.f, 0.f, 0.f, 0.f, 0.f, 0.f};

    #pragma unroll
    for (int m = 0; m < 8; ++m) {
        const float c1  = cb[m * 4 + 1];
        const int   y0  = (int)c1;         // trunc (coords >= 0)
        const int   srl = r0 - y0;         // source row of strip row 0
        if (srl + 7 < 0 || srl >= 64) continue;   // scalar branch (~5.5/8 m)

        const float c0 = cb[m * 4 + 0];
        const int   x0 = (int)c0;
        const int   sc = col - x0;
        if (sc < 0 || sc >= 64) continue;  // divergent; execz skips many waves

        const float c2 = cb[m * 4 + 2];
        const float c3 = cb[m * 4 + 3];
        const float xm = clamp01(fc - c0 + 1.f) * clamp01(c2 + 1.f - fc);

        const float* p = ib + m * (3 * 4096) + srl * 64 + sc;

        #pragma unroll
        for (int k = 0; k < 8; ++k) {
            const int sr = srl + k;            // block-uniform validity
            if (sr < 0 || sr >= 64) continue;  // scalar branch
            const float fr = (float)(r0 + k);
            const float ym = clamp01(fr - c1 + 1.f) * clamp01(c3 + 1.f - fr);
            const float* q = p + k * 64;
            const float s = q[0] + q[4096] + q[2 * 4096];   // 3 coalesced dwords
            acc[k] = fmaf(xm * ym, s, acc[k]);
        }
    }

    float* o = out + (size_t)n * 65536 + (size_t)r0 * 256 + col;
    #pragma unroll
    for (int k = 0; k < 8; ++k)
        o[k * 256] = fminf(1.f, acc[k]);
}

extern "C" void kernel_launch(void* const* d_in, const int* in_sizes, int n_in,
                              void* d_out, int out_size, void* d_ws, size_t ws_size,
                              hipStream_t stream) {
    const float* coords = (const float*)d_in[0];
    const float* images = (const float*)d_in[1];
    float* out = (float*)d_out;

    // 64 batches * 32 bands of 8 rows; 256 threads = one column each.
    Paste2dMulti_kernel<<<64 * 32, 256, 0, stream>>>(coords, images, out);
}

// Round 6
// 13.688 us; speedup vs baseline: 1.4534x; 1.4534x over previous
//
#include <hip/hip_runtime.h>

// Paste2dMulti: N=64, M=8, C=3, H=W=64, canvas l=256.
// Gather form. Thread = one output column x 4-row vertical strip (R3 winner).
// Hybrid load scheme: wave-level skip via __any(valid) (exec stays FULL
// inside -> branch-free body), source col clamped so every lane issues a
// legal load (clamped lanes alias the boundary dword -> same 64B segment,
// ~no extra transactions), invalid lanes zeroed by one v_cndmask folded
// into the x-mask. Surviving m's loads can overlap in flight (one vmcnt
// round trip instead of two). Nontemporal stores for write-once output.

__device__ __forceinline__ float clamp01(float v) {
    return fminf(fmaxf(v, 0.0f), 1.0f);   // -> v_med3_f32
}

__global__ __launch_bounds__(256) void Paste2dMulti_kernel(
    const float* __restrict__ coords,   // [64][8][4]
    const float* __restrict__ images,   // [64][8][3][64][64]
    float* __restrict__ out)            // [64][1][256][256]
{
    const int bid  = blockIdx.x;       // 64 n * 64 bands
    const int n    = bid >> 6;         // block-uniform
    const int band = bid & 63;
    const int col  = threadIdx.x;      // 0..255; each wave = 64 consecutive cols
    const int r0   = band * 4;         // rows r0 .. r0+3 (block-uniform)

    const float fc = (float)col;
    const float* cb = coords + n * 32;
    const float* ib = images + (size_t)n * (8 * 3 * 4096);

    float acc0 = 0.f, acc1 = 0.f, acc2 = 0.f, acc3 = 0.f;

    #pragma unroll
    for (int m = 0; m < 8; ++m) {
        const float c1  = cb[m * 4 + 1];
        const int   y0  = (int)c1;         // trunc (coords >= 0)
        const int   srl = r0 - y0;         // source row of strip row 0
        if (srl + 3 < 0 || srl >= 64) continue;   // scalar (block-uniform) skip

        const float c0 = cb[m * 4 + 0];
        const int   x0 = (int)c0;
        const int   sc = col - x0;
        const bool  valid = (unsigned)sc < 64u;
        if (!__any(valid)) continue;       // wave-uniform skip; exec full inside

        const float c2 = cb[m * 4 + 2];
        const float c3 = cb[m * 4 + 3];
        float xm = clamp01(fc - c0 + 1.f) * clamp01(c2 + 1.f - fc);
        xm = valid ? xm : 0.f;             // one v_cndmask, no divergent branch

        const int  scc = min(max(sc, 0), 63);     // always-legal source col
        const float* p = ib + m * (3 * 4096) + srl * 64 + scc;

        #pragma unroll
        for (int k = 0; k < 4; ++k) {
            const int sr = srl + k;            // block-uniform validity
            if (sr < 0 || sr >= 64) continue;  // scalar branch
            const float fr = (float)(r0 + k);
            const float ym = clamp01(fr - c1 + 1.f) * clamp01(c3 + 1.f - fr);
            const float* q = p + k * 64;
            const float s = q[0] + q[4096] + q[2 * 4096];   // 3 coalesced dwords
            const float w = xm * ym;
            if (k == 0) acc0 = fmaf(w, s, acc0);
            if (k == 1) acc1 = fmaf(w, s, acc1);
            if (k == 2) acc2 = fmaf(w, s, acc2);
            if (k == 3) acc3 = fmaf(w, s, acc3);
        }
    }

    float* o = out + (size_t)n * 65536 + (size_t)r0 * 256 + col;
    __builtin_nontemporal_store(fminf(1.f, acc0), o);
    __builtin_nontemporal_store(fminf(1.f, acc1), o + 256);
    __builtin_nontemporal_store(fminf(1.f, acc2), o + 512);
    __builtin_nontemporal_store(fminf(1.f, acc3), o + 768);
}

extern "C" void kernel_launch(void* const* d_in, const int* in_sizes, int n_in,
                              void* d_out, int out_size, void* d_ws, size_t ws_size,
                              hipStream_t stream) {
    const float* coords = (const float*)d_in[0];
    const float* images = (const float*)d_in[1];
    float* out = (float*)d_out;

    // 64 batches * 64 bands of 4 rows; 256 threads = one column each.
    Paste2dMulti_kernel<<<64 * 64, 256, 0, stream>>>(coords, images, out);
}